// Round 5
// baseline (632.562 us; speedup 1.0000x reference)
//
#include <hip/hip_runtime.h>
#include <stdint.h>

#define HMAP   (1u << 19)
#define HMASK  (HMAP - 1u)

typedef short bf16x8 __attribute__((ext_vector_type(8)));
typedef float f32x4  __attribute__((ext_vector_type(4)));

// resolutions: ceil(16 * 2^(7l/15)); dense (R^3 <= 2^19) for levels 0..4
__device__ __constant__ const int c_res[16] = {16, 23, 31, 43, 59, 81, 112, 154, 213, 295, 407, 562, 777, 1073, 1483, 2048};

__device__ __forceinline__ unsigned short f2bf(float f) {
    unsigned u = __float_as_uint(f);
    u += 0x7fffu + ((u >> 16) & 1u);           // round-to-nearest-even
    return (unsigned short)(u >> 16);
}

// Exactly matches where(100v>20, v, log1p(exp(100v))/100):
// softplus(t) = max(t,0) + log1p(exp(-|t|)); branchless, native exp/log only.
__device__ __forceinline__ float softplus100(float v) {
    return fmaxf(v, 0.f) + 0.01f * __logf(1.f + __expf(-100.f * fabsf(v)));
}

__device__ __forceinline__ bf16x8 cvt8(const float* __restrict__ p) {
    f32x4 a = *(const f32x4*)p;
    f32x4 b = *(const f32x4*)(p + 4);
    bf16x8 r;
    r[0] = f2bf(a[0]); r[1] = f2bf(a[1]); r[2] = f2bf(a[2]); r[3] = f2bf(a[3]);
    r[4] = f2bf(b[0]); r[5] = f2bf(b[1]); r[6] = f2bf(b[2]); r[7] = f2bf(b[3]);
    return r;
}

// Trilinear gather with x-corner pair packing (hashed: h(x+1)=h(x)^1 for even x
// -> one aligned 16B block; dense: idx adjacent, dwordx4 when idx even).
__device__ __forceinline__ float2 gather_level(const float* __restrict__ tab, int R,
                                               float x0, float x1, float x2) {
    const float Rm1 = (float)(R - 1);
    float px = x0 * Rm1, py = x1 * Rm1, pz = x2 * Rm1;
    float fx = floorf(px), fy = floorf(py), fz = floorf(pz);
    float wx = px - fx, wy = py - fy, wz = pz - fz;
    int ix = (int)fx, iy = (int)fy, iz = (int)fz;
    ix = max(0, min(ix, R - 1)); iy = max(0, min(iy, R - 1)); iz = max(0, min(iz, R - 1));
    int jx = min(ix + 1, R - 1), jy = min(iy + 1, R - 1), jz = min(iz + 1, R - 1);
    float ax = 1.f - wx, ay = 1.f - wy, az = 1.f - wz;
    float wyz0 = ay * az, wyz1 = wy * az, wyz2 = ay * wz, wyz3 = wy * wz;
    float2 lo[4], hi[4];
    const bool adj = (jx == ix + 1);
    if ((long long)R * R * R <= (long long)HMAP) {   // dense (uniform per level)
        unsigned sy = (unsigned)R, sz = (unsigned)(R * R);
        unsigned base0 = (unsigned)iy * sy + (unsigned)iz * sz;
        unsigned base1 = (unsigned)jy * sy + (unsigned)iz * sz;
        unsigned base2 = (unsigned)iy * sy + (unsigned)jz * sz;
        unsigned base3 = (unsigned)jy * sy + (unsigned)jz * sz;
        unsigned bases[4] = {base0, base1, base2, base3};
        const float2* t2 = (const float2*)tab;
        #pragma unroll
        for (int k = 0; k < 4; ++k) {
            unsigned i0 = bases[k] + (unsigned)ix;
            if (adj && !(i0 & 1u)) {
                f32x4 q = *(const f32x4*)(tab + ((size_t)i0 << 1));
                lo[k] = make_float2(q[0], q[1]);
                hi[k] = make_float2(q[2], q[3]);
            } else {
                lo[k] = t2[i0];
                hi[k] = t2[bases[k] + (unsigned)jx];
            }
        }
    } else {                                          // hashed
        unsigned hy0 = (unsigned)iy * 2654435761u, hy1 = (unsigned)jy * 2654435761u;
        unsigned hz0 = (unsigned)iz * 805459861u,  hz1 = (unsigned)jz * 805459861u;
        unsigned ms[4] = {hy0 ^ hz0, hy1 ^ hz0, hy0 ^ hz1, hy1 ^ hz1};
        if (adj && ((ix & 1) == 0)) {
            #pragma unroll
            for (int k = 0; k < 4; ++k) {
                unsigned h = ((unsigned)ix ^ ms[k]) & HMASK;
                f32x4 q = *(const f32x4*)(tab + ((size_t)(h & ~1u) << 1));
                float2 e0 = make_float2(q[0], q[1]);
                float2 e1 = make_float2(q[2], q[3]);
                bool sw = (h & 1u) != 0;
                lo[k] = sw ? e1 : e0;
                hi[k] = sw ? e0 : e1;
            }
        } else {
            const float2* t2 = (const float2*)tab;
            #pragma unroll
            for (int k = 0; k < 4; ++k) {
                unsigned hl = ((unsigned)ix ^ ms[k]) & HMASK;
                unsigned hh = ((unsigned)jx ^ ms[k]) & HMASK;
                lo[k] = t2[hl];
                hi[k] = t2[hh];
            }
        }
    }
    float2 r = make_float2(0.f, 0.f);
    float wyz[4] = {wyz0, wyz1, wyz2, wyz3};
    #pragma unroll
    for (int k = 0; k < 4; ++k) {
        float wl = ax * wyz[k], wh = wx * wyz[k];
        r.x += wl * lo[k].x + wh * hi[k].x;
        r.y += wl * lo[k].y + wh * hi[k].y;
    }
    return r;
}

// ======================= Kernel 1: per-(point,level) gather =======================
// phase0: level = b%8; phase1: level = 15-(b%8) -> XCD k serves levels {k, 15-k},
// each 4MB table L2-resident on one XCD. Chunked: p0 = chunk point offset.
__global__ __launch_bounds__(256, 8)
void gather_levels(const float* __restrict__ x, const float* __restrict__ tables,
                   unsigned* __restrict__ feat, int N, int C, int p0) {
    const int b = blockIdx.x;
    const int half = 8 * C;
    int r, level;
    if (b < half) { r = b; level = r & 7; }
    else          { r = b - half; level = 15 - (r & 7); }
    const size_t p = (size_t)p0 + (size_t)(r >> 3) * 256 + threadIdx.x;
    const float x0 = __builtin_nontemporal_load(x + 3 * p);
    const float x1 = __builtin_nontemporal_load(x + 3 * p + 1);
    const float x2 = __builtin_nontemporal_load(x + 3 * p + 2);
    float2 f = gather_level(tables + (size_t)level * (2u * HMAP), c_res[level], x0, x1, x2);
    unsigned v = (unsigned)f2bf(f.x) | ((unsigned)f2bf(f.y) << 16);
    __builtin_nontemporal_store(v, feat + (size_t)level * N + p);   // coalesced 4B/lane
}

// ======================= Kernel 2: tiled embed + MFMA MLP =======================
#define NPB       128
#define TILES     8
#define PTS_BLK   (NPB * TILES)           // 1024 points per block
#define SA_STRIDE 104
#define SW0_OFF   (128 * 104)
#define SMEM_SHORTS (SW0_OFF + 64 * 104)  // 39936 B -> 4 blocks/CU

__global__ __launch_bounds__(256, 4)
void mlp_tiled(const float* __restrict__ x, const unsigned* __restrict__ feat,
               const float* __restrict__ W0, const float* __restrict__ b0,
               const float* __restrict__ W1, const float* __restrict__ b1,
               const float* __restrict__ W2, const float* __restrict__ b2,
               float* __restrict__ out, int N, int p0) {
    __shared__ unsigned short smem[SMEM_SHORTS];
    const int tid  = threadIdx.x;
    const int blk  = blockIdx.x;
    const int wave = tid >> 6, lane = tid & 63;
    const int mhalf = (wave & 1) * 64;
    const int nhalf = (wave >> 1);
    const int lrow = lane & 15, quad = lane >> 4;

    for (int i = tid; i < 64 * 104; i += 256) {
        int n = i / 104, k = i - n * 104;
        smem[SW0_OFF + i] = (k < 71) ? f2bf(W0[n * 71 + k]) : (unsigned short)0;
    }
    for (int i = tid; i < 128 * 25; i += 256) {
        int p = i / 25, k = i - p * 25;
        smem[p * SA_STRIDE + 71 + k] = 0;
    }
    bf16x8 w1f[2][2];
    #pragma unroll
    for (int ks = 0; ks < 2; ++ks)
        #pragma unroll
        for (int nt = 0; nt < 2; ++nt) {
            int n = nhalf * 32 + nt * 16 + lrow;
            w1f[ks][nt] = cvt8(W1 + n * 64 + ks * 32 + quad * 8);
        }
    bf16x8 w2f[2];
    {
        int n2 = nhalf * 16 + lrow;
        #pragma unroll
        for (int ks = 0; ks < 2; ++ks) {
            if (n2 < 17) w2f[ks] = cvt8(W2 + n2 * 64 + ks * 32 + quad * 8);
            else { bf16x8 z = {0,0,0,0,0,0,0,0}; w2f[ks] = z; }
        }
    }
    float b0v[2], b1v[2], b2v;
    #pragma unroll
    for (int nt = 0; nt < 2; ++nt) {
        b0v[nt] = b0[nhalf * 32 + nt * 16 + lrow];
        b1v[nt] = b1[nhalf * 32 + nt * 16 + lrow];
    }
    { int c2 = nhalf * 16 + lrow; b2v = (c2 < 17) ? b2[c2] : 0.f; }
    __syncthreads();

    const size_t pbase0 = (size_t)p0 + (size_t)blk * PTS_BLK;
    #pragma unroll 1
    for (int t = 0; t < TILES; ++t) {
        const size_t pb = pbase0 + (size_t)t * NPB;
        {
            const int p = tid & 127;
            const size_t gp = pb + p;
            unsigned short* row = &smem[p * SA_STRIDE];
            const float x0 = __builtin_nontemporal_load(x + 3 * gp);
            const float x1 = __builtin_nontemporal_load(x + 3 * gp + 1);
            const float x2 = __builtin_nontemporal_load(x + 3 * gp + 2);
            if (tid < 128) {
                row[0] = f2bf(x0); row[1] = f2bf(x1); row[2] = f2bf(x2);
                float fr = 1.f;
                #pragma unroll
                for (int m = 0; m < 6; ++m) {
                    row[3 + 6 * m + 0] = f2bf(__sinf(x0 * fr));
                    row[3 + 6 * m + 1] = f2bf(__sinf(x1 * fr));
                    row[3 + 6 * m + 2] = f2bf(__sinf(x2 * fr));
                    fr *= 2.f;
                }
            } else {
                float fr = 1.f;
                #pragma unroll
                for (int m = 0; m < 6; ++m) {
                    row[3 + 6 * m + 3] = f2bf(__cosf(x0 * fr));
                    row[3 + 6 * m + 4] = f2bf(__cosf(x1 * fr));
                    row[3 + 6 * m + 5] = f2bf(__cosf(x2 * fr));
                    fr *= 2.f;
                }
                #pragma unroll
                for (int l = 0; l < 16; ++l) {
                    unsigned v = __builtin_nontemporal_load(feat + (size_t)l * N + gp);
                    row[39 + 2 * l] = (unsigned short)(v & 0xffffu);
                    row[40 + 2 * l] = (unsigned short)(v >> 16);
                }
            }
        }
        __syncthreads();

        f32x4 acc0[4][2];
        #pragma unroll
        for (int mt = 0; mt < 4; ++mt)
            #pragma unroll
            for (int nt = 0; nt < 2; ++nt) acc0[mt][nt] = (f32x4){0.f, 0.f, 0.f, 0.f};
        #pragma unroll
        for (int ks = 0; ks < 3; ++ks) {
            bf16x8 bfr[2];
            #pragma unroll
            for (int nt = 0; nt < 2; ++nt) {
                int n = nhalf * 32 + nt * 16 + lrow;
                bfr[nt] = *(const bf16x8*)&smem[SW0_OFF + n * 104 + ks * 32 + quad * 8];
            }
            #pragma unroll
            for (int mt = 0; mt < 4; ++mt) {
                int m = mhalf + mt * 16 + lrow;
                bf16x8 afr = *(const bf16x8*)&smem[m * SA_STRIDE + ks * 32 + quad * 8];
                #pragma unroll
                for (int nt = 0; nt < 2; ++nt)
                    acc0[mt][nt] = __builtin_amdgcn_mfma_f32_16x16x32_bf16(afr, bfr[nt], acc0[mt][nt], 0, 0, 0);
            }
        }
        __syncthreads();
        #pragma unroll
        for (int mt = 0; mt < 4; ++mt)
            #pragma unroll
            for (int nt = 0; nt < 2; ++nt) {
                int colg = nhalf * 32 + nt * 16 + lrow;
                #pragma unroll
                for (int r = 0; r < 4; ++r) {
                    int rowm = mhalf + mt * 16 + quad * 4 + r;
                    smem[rowm * SA_STRIDE + colg] = f2bf(softplus100(acc0[mt][nt][r] + b0v[nt]));
                }
            }
        __syncthreads();

        f32x4 acc1[4][2];
        #pragma unroll
        for (int mt = 0; mt < 4; ++mt)
            #pragma unroll
            for (int nt = 0; nt < 2; ++nt) acc1[mt][nt] = (f32x4){0.f, 0.f, 0.f, 0.f};
        #pragma unroll
        for (int ks = 0; ks < 2; ++ks) {
            #pragma unroll
            for (int mt = 0; mt < 4; ++mt) {
                int m = mhalf + mt * 16 + lrow;
                bf16x8 afr = *(const bf16x8*)&smem[m * SA_STRIDE + ks * 32 + quad * 8];
                #pragma unroll
                for (int nt = 0; nt < 2; ++nt)
                    acc1[mt][nt] = __builtin_amdgcn_mfma_f32_16x16x32_bf16(afr, w1f[ks][nt], acc1[mt][nt], 0, 0, 0);
            }
        }
        __syncthreads();
        #pragma unroll
        for (int mt = 0; mt < 4; ++mt)
            #pragma unroll
            for (int nt = 0; nt < 2; ++nt) {
                int colg = nhalf * 32 + nt * 16 + lrow;
                #pragma unroll
                for (int r = 0; r < 4; ++r) {
                    int rowm = mhalf + mt * 16 + quad * 4 + r;
                    smem[rowm * SA_STRIDE + colg] = f2bf(softplus100(acc1[mt][nt][r] + b1v[nt]));
                }
            }
        __syncthreads();

        f32x4 acc2[4];
        #pragma unroll
        for (int mt = 0; mt < 4; ++mt) acc2[mt] = (f32x4){0.f, 0.f, 0.f, 0.f};
        #pragma unroll
        for (int ks = 0; ks < 2; ++ks) {
            #pragma unroll
            for (int mt = 0; mt < 4; ++mt) {
                int m = mhalf + mt * 16 + lrow;
                bf16x8 afr = *(const bf16x8*)&smem[m * SA_STRIDE + ks * 32 + quad * 8];
                acc2[mt] = __builtin_amdgcn_mfma_f32_16x16x32_bf16(afr, w2f[ks], acc2[mt], 0, 0, 0);
            }
        }
        {
            int colg = nhalf * 16 + lrow;
            if (colg < 17) {
                #pragma unroll
                for (int mt = 0; mt < 4; ++mt)
                    #pragma unroll
                    for (int r = 0; r < 4; ++r) {
                        int rowm = mhalf + mt * 16 + quad * 4 + r;
                        __builtin_nontemporal_store(acc2[mt][r] + b2v,
                                                    out + (pb + rowm) * 17 + colg);
                    }
            }
        }
        __syncthreads();
    }
}

// ======================= Fallback (ws too small): fully fused =======================
__global__ __launch_bounds__(256, 3)
void gn_fused(const float* __restrict__ x, const float* __restrict__ tables,
              const float* __restrict__ W0, const float* __restrict__ b0,
              const float* __restrict__ W1, const float* __restrict__ b1,
              const float* __restrict__ W2, const float* __restrict__ b2,
              float* __restrict__ out) {
    __shared__ unsigned short smem[SMEM_SHORTS];
    const int tid = threadIdx.x;
    const int blk = blockIdx.x;
    const int wave = tid >> 6, lane = tid & 63;
    const int mhalf = (wave & 1) * 64;
    const int nhalf = (wave >> 1);
    const int lrow = lane & 15, quad = lane >> 4;
    for (int i = tid; i < 64 * 104; i += 256) {
        int n = i / 104, k = i - n * 104;
        smem[SW0_OFF + i] = (k < 71) ? f2bf(W0[n * 71 + k]) : (unsigned short)0;
    }
    for (int i = tid; i < 128 * 25; i += 256) {
        int p = i / 25, k = i - p * 25;
        smem[p * SA_STRIDE + 71 + k] = 0;
    }
    bf16x8 w1f[2][2];
    #pragma unroll
    for (int ks = 0; ks < 2; ++ks)
        #pragma unroll
        for (int nt = 0; nt < 2; ++nt) {
            int n = nhalf * 32 + nt * 16 + lrow;
            w1f[ks][nt] = cvt8(W1 + n * 64 + ks * 32 + quad * 8);
        }
    bf16x8 w2f[2];
    {
        int n2 = nhalf * 16 + lrow;
        #pragma unroll
        for (int ks = 0; ks < 2; ++ks) {
            if (n2 < 17) w2f[ks] = cvt8(W2 + n2 * 64 + ks * 32 + quad * 8);
            else { bf16x8 z = {0,0,0,0,0,0,0,0}; w2f[ks] = z; }
        }
    }
    float b0v[2], b1v[2], b2v;
    #pragma unroll
    for (int nt = 0; nt < 2; ++nt) {
        b0v[nt] = b0[nhalf * 32 + nt * 16 + lrow];
        b1v[nt] = b1[nhalf * 32 + nt * 16 + lrow];
    }
    { int c2 = nhalf * 16 + lrow; b2v = (c2 < 17) ? b2[c2] : 0.f; }
    {
        const int p = tid & 127;
        const size_t gp = (size_t)blk * NPB + p;
        const float x0 = x[3 * gp], x1 = x[3 * gp + 1], x2 = x[3 * gp + 2];
        unsigned short* row = &smem[p * SA_STRIDE];
        if (tid < 128) {
            row[0] = f2bf(x0); row[1] = f2bf(x1); row[2] = f2bf(x2);
            float fr = 1.f;
            #pragma unroll
            for (int m = 0; m < 6; ++m) {
                row[3 + 6 * m + 0] = f2bf(__sinf(x0 * fr));
                row[3 + 6 * m + 1] = f2bf(__sinf(x1 * fr));
                row[3 + 6 * m + 2] = f2bf(__sinf(x2 * fr));
                fr *= 2.f;
            }
            #pragma unroll
            for (int li = 0; li < 8; ++li) {
                const int l = 2 * li;
                float2 f = gather_level(tables + (size_t)l * (2u * HMAP), c_res[l], x0, x1, x2);
                row[39 + 2 * l] = f2bf(f.x);
                row[40 + 2 * l] = f2bf(f.y);
            }
        } else {
            float fr = 1.f;
            #pragma unroll
            for (int m = 0; m < 6; ++m) {
                row[3 + 6 * m + 3] = f2bf(__cosf(x0 * fr));
                row[3 + 6 * m + 4] = f2bf(__cosf(x1 * fr));
                row[3 + 6 * m + 5] = f2bf(__cosf(x2 * fr));
                fr *= 2.f;
            }
            #pragma unroll
            for (int li = 0; li < 8; ++li) {
                const int l = 2 * li + 1;
                float2 f = gather_level(tables + (size_t)l * (2u * HMAP), c_res[l], x0, x1, x2);
                row[39 + 2 * l] = f2bf(f.x);
                row[40 + 2 * l] = f2bf(f.y);
            }
        }
    }
    __syncthreads();
    f32x4 acc0[4][2];
    #pragma unroll
    for (int mt = 0; mt < 4; ++mt)
        #pragma unroll
        for (int nt = 0; nt < 2; ++nt) acc0[mt][nt] = (f32x4){0.f, 0.f, 0.f, 0.f};
    #pragma unroll
    for (int ks = 0; ks < 3; ++ks) {
        bf16x8 bfr[2];
        #pragma unroll
        for (int nt = 0; nt < 2; ++nt) {
            int n = nhalf * 32 + nt * 16 + lrow;
            bfr[nt] = *(const bf16x8*)&smem[SW0_OFF + n * 104 + ks * 32 + quad * 8];
        }
        #pragma unroll
        for (int mt = 0; mt < 4; ++mt) {
            int m = mhalf + mt * 16 + lrow;
            bf16x8 afr = *(const bf16x8*)&smem[m * SA_STRIDE + ks * 32 + quad * 8];
            #pragma unroll
            for (int nt = 0; nt < 2; ++nt)
                acc0[mt][nt] = __builtin_amdgcn_mfma_f32_16x16x32_bf16(afr, bfr[nt], acc0[mt][nt], 0, 0, 0);
        }
    }
    __syncthreads();
    #pragma unroll
    for (int mt = 0; mt < 4; ++mt)
        #pragma unroll
        for (int nt = 0; nt < 2; ++nt) {
            int colg = nhalf * 32 + nt * 16 + lrow;
            #pragma unroll
            for (int r = 0; r < 4; ++r) {
                int rowm = mhalf + mt * 16 + quad * 4 + r;
                smem[rowm * SA_STRIDE + colg] = f2bf(softplus100(acc0[mt][nt][r] + b0v[nt]));
            }
        }
    __syncthreads();
    f32x4 acc1[4][2];
    #pragma unroll
    for (int mt = 0; mt < 4; ++mt)
        #pragma unroll
        for (int nt = 0; nt < 2; ++nt) acc1[mt][nt] = (f32x4){0.f, 0.f, 0.f, 0.f};
    #pragma unroll
    for (int ks = 0; ks < 2; ++ks) {
        #pragma unroll
        for (int mt = 0; mt < 4; ++mt) {
            int m = mhalf + mt * 16 + lrow;
            bf16x8 afr = *(const bf16x8*)&smem[m * SA_STRIDE + ks * 32 + quad * 8];
            #pragma unroll
            for (int nt = 0; nt < 2; ++nt)
                acc1[mt][nt] = __builtin_amdgcn_mfma_f32_16x16x32_bf16(afr, w1f[ks][nt], acc1[mt][nt], 0, 0, 0);
        }
    }
    __syncthreads();
    #pragma unroll
    for (int mt = 0; mt < 4; ++mt)
        #pragma unroll
        for (int nt = 0; nt < 2; ++nt) {
            int colg = nhalf * 32 + nt * 16 + lrow;
            #pragma unroll
            for (int r = 0; r < 4; ++r) {
                int rowm = mhalf + mt * 16 + quad * 4 + r;
                smem[rowm * SA_STRIDE + colg] = f2bf(softplus100(acc1[mt][nt][r] + b1v[nt]));
            }
        }
    __syncthreads();
    f32x4 acc2[4];
    #pragma unroll
    for (int mt = 0; mt < 4; ++mt) acc2[mt] = (f32x4){0.f, 0.f, 0.f, 0.f};
    #pragma unroll
    for (int ks = 0; ks < 2; ++ks) {
        #pragma unroll
        for (int mt = 0; mt < 4; ++mt) {
            int m = mhalf + mt * 16 + lrow;
            bf16x8 afr = *(const bf16x8*)&smem[m * SA_STRIDE + ks * 32 + quad * 8];
            acc2[mt] = __builtin_amdgcn_mfma_f32_16x16x32_bf16(afr, w2f[ks], acc2[mt], 0, 0, 0);
        }
    }
    {
        int colg = nhalf * 16 + lrow;
        if (colg < 17) {
            #pragma unroll
            for (int mt = 0; mt < 4; ++mt)
                #pragma unroll
                for (int r = 0; r < 4; ++r) {
                    int rowm = mhalf + mt * 16 + quad * 4 + r;
                    out[((size_t)blk * NPB + rowm) * 17 + colg] = acc2[mt][r] + b2v;
                }
        }
    }
}

// ---- host-side pipeline resources (created once; GPU work identical every call) ----
#define NCHUNK 4
static hipStream_t g_s2 = nullptr;
static hipEvent_t  g_evFork = nullptr, g_evJoin = nullptr;
static hipEvent_t  g_ev1[NCHUNK];
static bool        g_init_ok = false;

static void pipeline_init() {
    if (g_s2) return;
    if (hipStreamCreateWithFlags(&g_s2, hipStreamNonBlocking) != hipSuccess) return;
    if (hipEventCreateWithFlags(&g_evFork, hipEventDisableTiming) != hipSuccess) return;
    if (hipEventCreateWithFlags(&g_evJoin, hipEventDisableTiming) != hipSuccess) return;
    for (int i = 0; i < NCHUNK; ++i)
        if (hipEventCreateWithFlags(&g_ev1[i], hipEventDisableTiming) != hipSuccess) return;
    g_init_ok = true;
}

extern "C" void kernel_launch(void* const* d_in, const int* in_sizes, int n_in,
                              void* d_out, int out_size, void* d_ws, size_t ws_size,
                              hipStream_t stream) {
    const float* x      = (const float*)d_in[0];
    const float* tables = (const float*)d_in[1];
    const float* W0     = (const float*)d_in[2];
    const float* b0     = (const float*)d_in[3];
    const float* W1     = (const float*)d_in[4];
    const float* b1     = (const float*)d_in[5];
    const float* W2     = (const float*)d_in[6];
    const float* b2     = (const float*)d_in[7];
    float* out = (float*)d_out;
    const int n = in_sizes[0] / 3;                       // 1048576
    const size_t ws_needed = (size_t)16 * n * 4;         // 64 MB feature staging
    if (ws_size < ws_needed) {
        gn_fused<<<dim3(n / NPB), dim3(256), 0, stream>>>(x, tables, W0, b0, W1, b1, W2, b2, out);
        return;
    }
    unsigned* feat = (unsigned*)d_ws;
    pipeline_init();
    if (g_init_ok && (n % (NCHUNK * PTS_BLK) == 0)) {
        // Pipelined: stream runs gather chunks back-to-back; s2 runs the MLP for
        // chunk c as soon as gather(c) completes -> gather(c+1) overlaps mlp(c).
        const int np = n / NCHUNK;
        const int C  = np / 256;
        hipEventRecord(g_evFork, stream);
        hipStreamWaitEvent(g_s2, g_evFork, 0);
        for (int c = 0; c < NCHUNK; ++c) {
            const int p0 = c * np;
            gather_levels<<<dim3(16 * C), dim3(256), 0, stream>>>(x, tables, feat, n, C, p0);
            hipEventRecord(g_ev1[c], stream);
            hipStreamWaitEvent(g_s2, g_ev1[c], 0);
            mlp_tiled<<<dim3(np / PTS_BLK), dim3(256), 0, g_s2>>>(x, feat, W0, b0, W1, b1, W2, b2, out, n, p0);
        }
        hipEventRecord(g_evJoin, g_s2);
        hipStreamWaitEvent(stream, g_evJoin, 0);
    } else {
        // Serial fallback on the provided stream.
        const int C = n / 256;
        gather_levels<<<dim3(16 * C), dim3(256), 0, stream>>>(x, tables, feat, n, C, 0);
        mlp_tiled<<<dim3(n / PTS_BLK), dim3(256), 0, stream>>>(x, feat, W0, b0, W1, b1, W2, b2, out, n, 0);
    }
}